// Round 9
// baseline (1021.568 us; speedup 1.0000x reference)
//
#include <hip/hip_runtime.h>

typedef unsigned short u16;
typedef __bf16 bf16x8 __attribute__((ext_vector_type(8)));
typedef float f32x4 __attribute__((ext_vector_type(4)));
typedef unsigned int u32;

#define EPSF 1e-6f

__device__ __forceinline__ u16 f2bf(float f) {
  union { float f; unsigned u; } un; un.f = f;
  unsigned r = un.u + 0x7FFFu + ((un.u >> 16) & 1u);
  return (u16)(r >> 16);
}

__device__ __forceinline__ float block_sum(float v) {
  #pragma unroll
  for (int off = 32; off > 0; off >>= 1) v += __shfl_xor(v, off, 64);
  __shared__ float ws[4];
  const int w = threadIdx.x >> 6;
  __syncthreads();
  if ((threadIdx.x & 63) == 0) ws[w] = v;
  __syncthreads();
  return ws[0] + ws[1] + ws[2] + ws[3];
}

// async global->LDS, 16B per lane. LDS dest must be wave-uniform base; HW adds lane*16.
__device__ __forceinline__ void lds_cp16(const void* g, void* l) {
  __builtin_amdgcn_global_load_lds(
      (__attribute__((address_space(1))) void*)g,
      (__attribute__((address_space(3))) void*)l, 16, 0, 0);
}

// ---------------- embedding + anorm(norm1_gain[0]) fused ----------------
__global__ __launch_bounds__(256) void embed_norm(
    const int* __restrict__ idx, const float* __restrict__ tok,
    const float* __restrict__ pos, const float* __restrict__ gain,
    float* __restrict__ x, u16* __restrict__ h) {
  const int row = blockIdx.x;
  const int tpos = row & 1023;
  const int token = idx[row];
  const int d = threadIdx.x * 4;
  const float4 a = *(const float4*)(tok + (long)token * 1024 + d);
  const float4 b = *(const float4*)(pos + (long)tpos * 1024 + d);
  float4 o; o.x = a.x + b.x; o.y = a.y + b.y; o.z = a.z + b.z; o.w = a.w + b.w;
  *(float4*)(x + (long)row * 1024 + d) = o;
  float s = fabsf(o.x) + fabsf(o.y) + fabsf(o.z) + fabsf(o.w);
  s = block_sum(s);
  const float scale = 1.0f / (s * (1.0f / 1024.0f) + EPSF);
  const float4 g = *(const float4*)(gain + d);
  ushort4 ov;
  ov.x = f2bf(o.x * g.x * scale);
  ov.y = f2bf(o.y * g.y * scale);
  ov.z = f2bf(o.z * g.z * scale);
  ov.w = f2bf(o.w * g.w * scale);
  *(ushort4*)(h + (long)row * 1024 + d) = ov;
}

// ---------------- anorm (standalone, for norm2) ----------------
__global__ __launch_bounds__(256) void anorm_kernel(
    const float* __restrict__ x, const float* __restrict__ gain,
    u16* __restrict__ h) {
  const int row = blockIdx.x;
  const int tid = threadIdx.x;
  const float4 v = *(const float4*)(x + (long)row * 1024 + tid * 4);
  float s = fabsf(v.x) + fabsf(v.y) + fabsf(v.z) + fabsf(v.w);
  s = block_sum(s);
  const float scale = 1.0f / (s * (1.0f / 1024.0f) + EPSF);
  const float4 g = *(const float4*)(gain + tid * 4);
  ushort4 o;
  o.x = f2bf(v.x * g.x * scale);
  o.y = f2bf(v.y * g.y * scale);
  o.z = f2bf(v.z * g.z * scale);
  o.w = f2bf(v.w * g.w * scale);
  *(ushort4*)(h + (long)row * 1024 + tid * 4) = o;
}

// =====================================================================
// Attention v4 (unchanged, proven): register-resident S.
// =====================================================================
__global__ __launch_bounds__(512, 4) void attn_v4(
    const u16* __restrict__ qkv, const u16* __restrict__ v_t,
    u16* __restrict__ obuf, const float* __restrict__ score_gain, int l) {
  __shared__ float red1[2][4][16], red2[2][4][16], red3[2][4][16];
  __shared__ float Ured[2][4][16][68];
  __shared__ u16 Pl[8][640];
  const int qt = blockIdx.x, h = blockIdx.y, b = blockIdx.z;
  const int tid = threadIdx.x, w = tid >> 6, l64 = tid & 63;
  const int lq = l64 & 15, kgrp = l64 >> 4;
  const int wq = w >> 2, tq = w & 3;
  const int qglob = qt * 32 + wq * 16 + lq;
  const int qmax  = qt * 32 + wq * 16 + 15;
  const int tbase = tq * 256;
  const u16* Qg = qkv + (size_t)b * (1024 * 3072) + h * 64;
  const u16* Kg = Qg + 1024;
  const u16* Vt = v_t + (size_t)(b * 16 + h) * (64 * 1024);
  char* Pw = (char*)&Pl[w][0];

  bf16x8 qB0, qB1;
  {
    const u16* qp = Qg + (size_t)qglob * 3072 + (kgrp << 3);
    qB0 = *(const bf16x8*)qp;
    qB1 = *(const bf16x8*)(qp + 32);
  }

  f32x4 s[16];
  {
    const u16* Kl = Kg + (size_t)(tbase + lq) * 3072 + (kgrp << 3);
    #pragma unroll
    for (int tile = 0; tile < 16; tile++) {
      const u16* kp = Kl + (size_t)tile * (16 * 3072);
      const bf16x8 k0 = *(const bf16x8*)kp;
      const bf16x8 k1 = *(const bf16x8*)(kp + 32);
      f32x4 d = {0.f, 0.f, 0.f, 0.f};
      d = __builtin_amdgcn_mfma_f32_16x16x32_bf16(k0, qB0, d, 0, 0, 0);
      d = __builtin_amdgcn_mfma_f32_16x16x32_bf16(k1, qB1, d, 0, 0, 0);
      s[tile] = d;
    }
  }

  float ssum = 0.f;
  #pragma unroll
  for (int tile = 0; tile < 16; tile++)
    ssum += (s[tile][0] + s[tile][1]) + (s[tile][2] + s[tile][3]);
  ssum += __shfl_xor(ssum, 16, 64);
  ssum += __shfl_xor(ssum, 32, 64);
  if (l64 < 16) red1[wq][tq][l64] = ssum;
  __syncthreads();
  const float mean = (red1[wq][0][lq] + red1[wq][1][lq] +
                      red1[wq][2][lq] + red1[wq][3][lq]) * (1.0f / 1024.0f);

  float asum = 0.f;
  #pragma unroll
  for (int tile = 0; tile < 16; tile++)
    asum += fabsf(s[tile][0] - mean) + fabsf(s[tile][1] - mean) +
            fabsf(s[tile][2] - mean) + fabsf(s[tile][3] - mean);
  asum += __shfl_xor(asum, 16, 64);
  asum += __shfl_xor(asum, 32, 64);
  if (l64 < 16) red2[wq][tq][l64] = asum;
  __syncthreads();
  const float mad = (red2[wq][0][lq] + red2[wq][1][lq] +
                     red2[wq][2][lq] + red2[wq][3][lq]) * (1.0f / 1024.0f) + EPSF;
  const float gs = score_gain[l] / mad;

  float psum = 0.f;
  #pragma unroll
  for (int tile = 0; tile < 16; tile++) {
    #pragma unroll
    for (int j = 0; j < 4; j++) {
      const int t = tbase + tile * 16 + (kgrp << 2) + j;
      float sv = (s[tile][j] - mean) * gs;
      if (t > qglob) sv = -1000.0f;
      const float rr = sv / (fabsf(sv) + 1.0f);
      const float a1 = (rr + 1.0f) * 0.5f;
      const float a2 = a1 * a1;
      s[tile][j] = a2 * a2;
      psum += s[tile][j];
    }
  }

  f32x4 U[4] = {};
  #pragma unroll
  for (int c = 0; c < 8; c++) {
    const int t0 = tbase + c * 32;
    if (t0 <= qmax) {
      #pragma unroll
      for (int half = 0; half < 2; half++) {
        #pragma unroll
        for (int pr = 0; pr < 2; pr++) {
          const u32 pk = (u32)f2bf(s[2 * c + half][pr * 2]) |
                         ((u32)f2bf(s[2 * c + half][pr * 2 + 1]) << 16);
          *(u32*)(Pw + lq * 80 + half * 32 + (kgrp << 3) + (pr << 2)) = pk;
        }
      }
      asm volatile("s_waitcnt lgkmcnt(0)" ::: "memory");
      __builtin_amdgcn_sched_barrier(0);
      const bf16x8 pB = *(const bf16x8*)(Pw + lq * 80 + (kgrp << 4));
      #pragma unroll
      for (int dt = 0; dt < 4; dt++) {
        const bf16x8 vA = *(const bf16x8*)(Vt + (size_t)((dt << 4) + lq) * 1024 +
                                           t0 + (kgrp << 3));
        U[dt] = __builtin_amdgcn_mfma_f32_16x16x32_bf16(vA, pB, U[dt], 0, 0, 0);
      }
    }
  }

  psum += __shfl_xor(psum, 16, 64);
  psum += __shfl_xor(psum, 32, 64);
  if (l64 < 16) red3[wq][tq][l64] = psum;
  #pragma unroll
  for (int dt = 0; dt < 4; dt++)
    *(float4*)&Ured[wq][tq][lq][(dt << 4) + (kgrp << 2)] = *(const float4*)&U[dt];
  __syncthreads();

  {
    const int qq = tid >> 4, dhseg = (tid & 15) << 2;
    const int fwq = qq >> 4, flq = qq & 15;
    const float fps = red3[fwq][0][flq] + red3[fwq][1][flq] +
                      red3[fwq][2][flq] + red3[fwq][3][flq];
    const float oinv = 1.0f / (fps + EPSF);
    float4 u0 = *(const float4*)&Ured[fwq][0][flq][dhseg];
    const float4 u1 = *(const float4*)&Ured[fwq][1][flq][dhseg];
    const float4 u2 = *(const float4*)&Ured[fwq][2][flq][dhseg];
    const float4 u3 = *(const float4*)&Ured[fwq][3][flq][dhseg];
    u0.x = (u0.x + u1.x + u2.x + u3.x) * oinv;
    u0.y = (u0.y + u1.y + u2.y + u3.y) * oinv;
    u0.z = (u0.z + u1.z + u2.z + u3.z) * oinv;
    u0.w = (u0.w + u1.w + u2.w + u3.w) * oinv;
    ushort4 o;
    o.x = f2bf(u0.x); o.y = f2bf(u0.y); o.z = f2bf(u0.z); o.w = f2bf(u0.w);
    u16* dst = obuf + ((size_t)((b << 10) + qt * 32 + qq) << 10) + (h << 6) + dhseg;
    *(ushort4*)dst = o;
  }
}

// ---------------- weight conversion: 64x64 tiles, ONE dispatch ----------------
__global__ void wconv_all(
    const float* __restrict__ Wq, const float* __restrict__ Wk,
    const float* __restrict__ Wv, const float* __restrict__ Wo,
    const float* __restrict__ W1, const float* __restrict__ W2,
    const float* __restrict__ Wlm,
    u16* __restrict__ wqkv_t, u16* __restrict__ wo_t,
    u16* __restrict__ w1_t, u16* __restrict__ w2_t, u16* __restrict__ wlm_t) {
  __shared__ float tile[64][65];
  const int bid = blockIdx.x;
  const float* src; u16* dst; int R, C, c0, r0;
  if (bid < 4096) {
    const int l = bid >> 10, m = (bid >> 8) & 3, t = bid & 255;
    if (m == 0)      src = Wq + (size_t)l * 1048576;
    else if (m == 1) src = Wk + (size_t)l * 1048576;
    else if (m == 2) src = Wv + (size_t)l * 1048576;
    else             src = Wo + (size_t)l * 1048576;
    dst = (m < 3) ? wqkv_t + ((size_t)l * 3072 + m * 1024) * 1024
                  : wo_t + (size_t)l * 1048576;
    R = 1024; C = 1024; c0 = (t & 15) << 6; r0 = (t >> 4) << 6;
  } else if (bid < 8192) {
    const int i = bid - 4096, l = i >> 10, t = i & 1023;
    src = W1 + (size_t)l * 4194304; dst = w1_t + (size_t)l * 4194304;
    R = 1024; C = 4096; c0 = (t & 63) << 6; r0 = (t >> 6) << 6;
  } else if (bid < 12288) {
    const int i = bid - 8192, l = i >> 10, t = i & 1023;
    src = W2 + (size_t)l * 4194304; dst = w2_t + (size_t)l * 4194304;
    R = 4096; C = 1024; c0 = (t & 15) << 6; r0 = (t >> 4) << 6;
  } else {
    const int i = bid - 12288;
    src = Wlm; dst = wlm_t;
    R = 1024; C = 32000; c0 = (i % 500) << 6; r0 = (i / 500) << 6;
  }
  const int tx = threadIdx.x, ty = threadIdx.y;   // (64,4)
  #pragma unroll
  for (int i = 0; i < 16; i++)
    tile[i * 4 + ty][tx] = src[(long)(r0 + i * 4 + ty) * C + c0 + tx];
  __syncthreads();
  #pragma unroll
  for (int i = 0; i < 16; i++)
    dst[(long)(c0 + i * 4 + ty) * R + r0 + tx] = f2bf(tile[tx][i * 4 + ty]);
}

__global__ __launch_bounds__(256) void bias_concat(
    const float* __restrict__ bq, const float* __restrict__ bk,
    const float* __restrict__ bv, float* __restrict__ out) {
  const int i = blockIdx.x * 256 + threadIdx.x;
  const int l = i / 3072, j = i % 3072;
  float v;
  if (j < 1024)      v = bq[l * 1024 + j];
  else if (j < 2048) v = bk[l * 1024 + j - 1024];
  else               v = bv[l * 1024 + j - 2048];
  out[i] = v;
}

// ---- FFN2 split-K=4 reduce + residual + anorm(next gain) fused ----
__global__ __launch_bounds__(256) void ffn2_reduce_norm(
    const float* __restrict__ part, const float* __restrict__ b2,
    float* __restrict__ x, const float* __restrict__ gain,
    u16* __restrict__ h) {
  const int row = blockIdx.x, c = threadIdx.x * 4;
  const float4 p0 = *(const float4*)(part + (size_t)row * 1024 + c);
  const float4 p1 = *(const float4*)(part + (size_t)(row + 2048) * 1024 + c);
  const float4 p2 = *(const float4*)(part + (size_t)(row + 4096) * 1024 + c);
  const float4 p3 = *(const float4*)(part + (size_t)(row + 6144) * 1024 + c);
  const float4 bb = *(const float4*)(b2 + c);
  float4 xv = *(float4*)(x + (size_t)row * 1024 + c);
  xv.x += (p0.x + p1.x) + (p2.x + p3.x) + bb.x;
  xv.y += (p0.y + p1.y) + (p2.y + p3.y) + bb.y;
  xv.z += (p0.z + p1.z) + (p2.z + p3.z) + bb.z;
  xv.w += (p0.w + p1.w) + (p2.w + p3.w) + bb.w;
  *(float4*)(x + (size_t)row * 1024 + c) = xv;
  float s = fabsf(xv.x) + fabsf(xv.y) + fabsf(xv.z) + fabsf(xv.w);
  s = block_sum(s);
  const float scale = 1.0f / (s * (1.0f / 1024.0f) + EPSF);
  const float4 g = *(const float4*)(gain + c);
  ushort4 o;
  o.x = f2bf(xv.x * g.x * scale);
  o.y = f2bf(xv.y * g.y * scale);
  o.z = f2bf(xv.z * g.z * scale);
  o.w = f2bf(xv.w * g.w * scale);
  *(ushort4*)(h + (size_t)row * 1024 + c) = o;
}

// =====================================================================
// 128x128-tile pipelined GEMM: 4 waves, BK=32, 4-deep 64KB LDS ring,
// 2 blocks/CU, counted vmcnt, swizzled. VTOUT: tiles with rowB0>=2048
// (V-projection) are transposed via LDS into v_t[(b*16+h)][dh][t].
// Requires M,N % 128 == 0, K % 32 == 0, K >= 96.
// =====================================================================
template <bool OUT_BF16, bool BIAS, bool RELU, bool RESID, bool VTOUT>
__global__ __launch_bounds__(256) void gemm128p(
    const u16* __restrict__ A, long lda, long sA,
    const u16* __restrict__ Bt, long ldb, long sB,
    void* __restrict__ Cv, long ldc, long sC,
    const float* __restrict__ bias, const float* __restrict__ resid,
    u16* __restrict__ vtout,
    int M, int N, int K, int nTM) {
  __shared__ u16 lds[32768];            // 4 slots x 16 KB (reused for VTOUT transpose)
  const int nwg = gridDim.x;
  const int qx = nwg >> 3, rx = nwg & 7;
  const int xcd = blockIdx.x & 7, seq = blockIdx.x >> 3;
  const int wg = (xcd < rx ? xcd * (qx + 1) : rx * (qx + 1) + (xcd - rx) * qx) + seq;
  const int tm = wg % nTM, tn = wg / nTM;
  const int batch = blockIdx.y;
  A  += (long)batch * sA;
  Bt += (long)batch * sB;
  const int rowA0 = tm * 128, rowB0 = tn * 128;
  const int t = threadIdx.x, w = t >> 6, l = t & 63;
  const int lrow = l & 15, kgrp = l >> 4;
  const int wr = (w >> 1) << 6, wc = (w & 1) << 6;

  const int srow = t >> 2;
  const int scol = ((t & 3) ^ ((t >> 3) & 3)) * 8;
  const u16* Asrc = A + (long)(rowA0 + srow) * lda + scol;
  const u16* Bsrc = Bt + (long)(rowB0 + srow) * ldb + scol;
  char* ldsB = (char*)lds;
  const int wbase = w * 1024;

  const int swz8 = (kgrp ^ ((lrow >> 1) & 3)) * 8;
  const int aoff = (wr + lrow) * 32 + swz8;
  const int boff = 4096 + (wc + lrow) * 32 + swz8;

  f32x4 acc[4][4] = {};
  const int NT = K >> 5;

  #pragma unroll
  for (int pt = 0; pt < 3; pt++) {
    const int k0 = pt << 5;
    const int bb = pt * 16384;
    lds_cp16(Asrc + k0,                   ldsB + bb + wbase);
    lds_cp16(Asrc + (long)64 * lda + k0,  ldsB + bb + 4096 + wbase);
    lds_cp16(Bsrc + k0,                   ldsB + bb + 8192 + wbase);
    lds_cp16(Bsrc + (long)64 * ldb + k0,  ldsB + bb + 12288 + wbase);
  }

  for (int tt = 0; tt < NT; tt++) {
    const int rem = NT - 1 - tt;
    if (rem >= 2)      asm volatile("s_waitcnt vmcnt(8)" ::: "memory");
    else if (rem == 1) asm volatile("s_waitcnt vmcnt(4)" ::: "memory");
    else               asm volatile("s_waitcnt vmcnt(0)" ::: "memory");
    __builtin_amdgcn_sched_barrier(0);
    __builtin_amdgcn_s_barrier();

    const u16* buf = lds + (tt & 3) * 8192;
    const int stage = tt + 3 < NT;
    const int k0n = (tt + 3) << 5;
    const int bbn = ((tt + 3) & 3) * 16384;

    bf16x8 aF[4], bF[4];
    #pragma unroll
    for (int m = 0; m < 4; m++) aF[m] = *(const bf16x8*)(buf + aoff + m * 512);
    #pragma unroll
    for (int n = 0; n < 4; n++) bF[n] = *(const bf16x8*)(buf + boff + n * 512);
    if (stage) {
      lds_cp16(Asrc + k0n,                  ldsB + bbn + wbase);
      lds_cp16(Asrc + (long)64 * lda + k0n, ldsB + bbn + 4096 + wbase);
      lds_cp16(Bsrc + k0n,                  ldsB + bbn + 8192 + wbase);
      lds_cp16(Bsrc + (long)64 * ldb + k0n, ldsB + bbn + 12288 + wbase);
    }
    asm volatile("s_waitcnt lgkmcnt(0)" ::: "memory");
    __builtin_amdgcn_sched_barrier(0);
    __builtin_amdgcn_s_setprio(1);
    #pragma unroll
    for (int m = 0; m < 4; m++)
      #pragma unroll
      for (int n = 0; n < 4; n++)
        acc[m][n] = __builtin_amdgcn_mfma_f32_16x16x32_bf16(aF[m], bF[n], acc[m][n], 0, 0, 0);
    __builtin_amdgcn_s_setprio(0);
  }

  if (VTOUT && rowB0 >= 2048) {
    // ---- transpose epilogue: acc -> LDS [col][row] -> v_t[(b*16+h)][dh][t] ----
    __syncthreads();                      // all K-loop LDS reads complete
    #pragma unroll
    for (int m = 0; m < 4; m++) {
      #pragma unroll
      for (int n = 0; n < 4; n++) {
        const int c = wc + n * 16 + lrow;
        const int r = wr + m * 16 + (kgrp << 2);
        ushort4 pk;
        float v0 = acc[m][n][0], v1 = acc[m][n][1], v2 = acc[m][n][2], v3 = acc[m][n][3];
        if (BIAS) {
          const float bv = bias[rowB0 + c];
          v0 += bv; v1 += bv; v2 += bv; v3 += bv;
        }
        pk.x = f2bf(v0); pk.y = f2bf(v1); pk.z = f2bf(v2); pk.w = f2bf(v3);
        *(ushort4*)&lds[c * 136 + r] = pk;
      }
    }
    __syncthreads();
    {
      const int c = t >> 1, half = t & 1;       // c = local col 0..127
      const int dh = c & 63;
      const int h = ((rowB0 - 2048) >> 6) + (c >> 6);
      const int bb2 = rowA0 >> 10, t0 = rowA0 & 1023;
      u16* dst = vtout + (((size_t)(bb2 * 16 + h)) << 16) + ((size_t)dh << 10) +
                 t0 + half * 64;
      #pragma unroll
      for (int k = 0; k < 8; k++)
        *(bf16x8*)(dst + k * 8) = *(const bf16x8*)&lds[c * 136 + half * 64 + k * 8];
    }
  } else {
    const long coff = (long)batch * sC;
    #pragma unroll
    for (int m = 0; m < 4; m++) {
      #pragma unroll
      for (int n = 0; n < 4; n++) {
        const int col = rowB0 + wc + n * 16 + lrow;
        #pragma unroll
        for (int j = 0; j < 4; j++) {
          const int row = rowA0 + wr + m * 16 + (kgrp << 2) + j;
          float v = acc[m][n][j];
          if (BIAS) v += bias[col];
          if (RELU) v = fmaxf(v, 0.0f);
          const long off = coff + (long)row * ldc + col;
          if (RESID) v += resid[off];
          if (OUT_BF16) ((u16*)Cv)[off] = f2bf(v);
          else          ((float*)Cv)[off] = v;
        }
      }
    }
  }
}

extern "C" void kernel_launch(void* const* d_in, const int* in_sizes, int n_in,
                              void* d_out, int out_size, void* d_ws, size_t ws_size,
                              hipStream_t stream) {
  constexpr int Lc = 4, Tc = 1024, Dc = 1024, Hc = 16, Fc = 4096, DHc = 64;
  const int M = 2 * Tc;

  const int*   idxp       = (const int*)  d_in[0];
  const float* tok_emb    = (const float*)d_in[1];
  const float* pos_emb    = (const float*)d_in[2];
  const float* Wq         = (const float*)d_in[3];
  const float* bq         = (const float*)d_in[4];
  const float* Wk         = (const float*)d_in[5];
  const float* bk         = (const float*)d_in[6];
  const float* Wv         = (const float*)d_in[7];
  const float* bv         = (const float*)d_in[8];
  const float* Wo         = (const float*)d_in[9];
  const float* bo         = (const float*)d_in[10];
  const float* score_gain = (const float*)d_in[11];
  const float* norm1_gain = (const float*)d_in[12];
  const float* norm2_gain = (const float*)d_in[13];
  const float* W1         = (const float*)d_in[14];
  const float* b1         = (const float*)d_in[15];
  const float* W2         = (const float*)d_in[16];
  const float* b2         = (const float*)d_in[17];
  const float* final_gain = (const float*)d_in[18];
  const float* Wlm        = (const float*)d_in[19];
  const float* blm        = (const float*)d_in[20];

  char* p = (char*)d_ws;
  auto alloc = [&](size_t n) { char* r = p; p += (n + 255) & ~(size_t)255; return r; };
  u16*  wqkv_t = (u16*) alloc((size_t)Lc * 3072 * 1024 * 2);
  u16*  wo_t   = (u16*) alloc((size_t)Lc * 1024 * 1024 * 2);
  u16*  w1_t   = (u16*) alloc((size_t)Lc * 4096 * 1024 * 2);
  u16*  w2_t   = (u16*) alloc((size_t)Lc * 1024 * 4096 * 2);
  u16*  wlm_t  = (u16*) alloc((size_t)32000 * 1024 * 2);
  float* bqkv  = (float*)alloc((size_t)Lc * 3072 * 4);
  float* x     = (float*)alloc((size_t)M * 1024 * 4);
  u16*  hbuf   = (u16*) alloc((size_t)M * 1024 * 2);
  u16*  qkv    = (u16*) alloc((size_t)M * 3072 * 2);
  u16*  v_t    = (u16*) alloc((size_t)2 * Hc * DHc * Tc * 2);
  u16*  obuf   = (u16*) alloc((size_t)M * 1024 * 2);
  u16*  ffh    = (u16*) alloc((size_t)M * 4096 * 2);
  float* fpart = (float*)alloc((size_t)4 * M * 1024 * 4);

  wconv_all<<<20288, dim3(64, 4), 0, stream>>>(Wq, Wk, Wv, Wo, W1, W2, Wlm,
                                               wqkv_t, wo_t, w1_t, w2_t, wlm_t);
  bias_concat<<<48, 256, 0, stream>>>(bq, bk, bv, bqkv);
  embed_norm<<<M, 256, 0, stream>>>(idxp, tok_emb, pos_emb, norm1_gain, x, hbuf);

  for (int l = 0; l < Lc; l++) {
    // QKV (V columns transposed straight into v_t via LDS epilogue)
    gemm128p<true, true, false, false, true><<<dim3(16 * 24, 1), 256, 0, stream>>>(
        hbuf, 1024, 0, wqkv_t + (size_t)l * 3072 * 1024, 1024, 0,
        qkv, 3072, 0, bqkv + (size_t)l * 3072, nullptr, v_t, M, 3072, 1024, 16);

    attn_v4<<<dim3(32, 16, 2), 512, 0, stream>>>(qkv, v_t, obuf, score_gain, l);

    gemm128p<false, true, false, true, false><<<dim3(16 * 8, 1), 256, 0, stream>>>(
        obuf, 1024, 0, wo_t + (size_t)l * 1024 * 1024, 1024, 0,
        x, 1024, 0, bo + (size_t)l * 1024, x, nullptr, M, 1024, 1024, 16);
    anorm_kernel<<<M, 256, 0, stream>>>(x, norm2_gain + (size_t)l * Dc, hbuf);
    // FFN1: grid 512, 2 blocks/CU
    gemm128p<true, true, true, false, false><<<dim3(16 * 32, 1), 256, 0, stream>>>(
        hbuf, 1024, 0, w1_t + (size_t)l * Fc * Dc, 1024, 0,
        ffh, 4096, 0, b1 + (size_t)l * Fc, nullptr, nullptr, M, 4096, 1024, 16);
    // FFN2 split-K=4: grid (128,4), K=1024 each
    gemm128p<false, false, false, false, false><<<dim3(128, 4), 256, 0, stream>>>(
        ffh, 4096, 1024, w2_t + (size_t)l * Dc * Fc, 4096, 1024,
        fpart, 1024, (long)M * 1024, nullptr, nullptr, nullptr, M, 1024, 1024, 16);
    const float* gnext = (l < Lc - 1) ? (norm1_gain + (size_t)(l + 1) * Dc) : final_gain;
    ffn2_reduce_norm<<<M, 256, 0, stream>>>(fpart, b2 + (size_t)l * Dc, x, gnext, hbuf);
  }

  // LM head on gemm128p: grid 16 x 250 = 4000 blocks, 2 blocks/CU
  gemm128p<false, true, false, false, false><<<dim3(16 * 250, 1), 256, 0, stream>>>(
      hbuf, 1024, 0, wlm_t, 1024, 0,
      d_out, 32000, 0, blm, nullptr, nullptr, M, 32000, 1024, 16);
}

// Round 10
// 990.917 us; speedup vs baseline: 1.0309x; 1.0309x over previous
//
#include <hip/hip_runtime.h>

typedef unsigned short u16;
typedef __bf16 bf16x8 __attribute__((ext_vector_type(8)));
typedef float f32x4 __attribute__((ext_vector_type(4)));
typedef unsigned int u32;

#define EPSF 1e-6f

__device__ __forceinline__ u16 f2bf(float f) {
  union { float f; unsigned u; } un; un.f = f;
  unsigned r = un.u + 0x7FFFu + ((un.u >> 16) & 1u);
  return (u16)(r >> 16);
}

__device__ __forceinline__ float block_sum(float v) {
  #pragma unroll
  for (int off = 32; off > 0; off >>= 1) v += __shfl_xor(v, off, 64);
  __shared__ float ws[4];
  const int w = threadIdx.x >> 6;
  __syncthreads();
  if ((threadIdx.x & 63) == 0) ws[w] = v;
  __syncthreads();
  return ws[0] + ws[1] + ws[2] + ws[3];
}

// async global->LDS, 16B per lane. LDS dest must be wave-uniform base; HW adds lane*16.
__device__ __forceinline__ void lds_cp16(const void* g, void* l) {
  __builtin_amdgcn_global_load_lds(
      (__attribute__((address_space(1))) void*)g,
      (__attribute__((address_space(3))) void*)l, 16, 0, 0);
}

// ---------------- embedding + anorm(norm1_gain[0]) fused ----------------
__global__ __launch_bounds__(256) void embed_norm(
    const int* __restrict__ idx, const float* __restrict__ tok,
    const float* __restrict__ pos, const float* __restrict__ gain,
    float* __restrict__ x, u16* __restrict__ h) {
  const int row = blockIdx.x;
  const int tpos = row & 1023;
  const int token = idx[row];
  const int d = threadIdx.x * 4;
  const float4 a = *(const float4*)(tok + (long)token * 1024 + d);
  const float4 b = *(const float4*)(pos + (long)tpos * 1024 + d);
  float4 o; o.x = a.x + b.x; o.y = a.y + b.y; o.z = a.z + b.z; o.w = a.w + b.w;
  *(float4*)(x + (long)row * 1024 + d) = o;
  float s = fabsf(o.x) + fabsf(o.y) + fabsf(o.z) + fabsf(o.w);
  s = block_sum(s);
  const float scale = 1.0f / (s * (1.0f / 1024.0f) + EPSF);
  const float4 g = *(const float4*)(gain + d);
  ushort4 ov;
  ov.x = f2bf(o.x * g.x * scale);
  ov.y = f2bf(o.y * g.y * scale);
  ov.z = f2bf(o.z * g.z * scale);
  ov.w = f2bf(o.w * g.w * scale);
  *(ushort4*)(h + (long)row * 1024 + d) = ov;
}

// ---------------- anorm (standalone, for norm2) ----------------
__global__ __launch_bounds__(256) void anorm_kernel(
    const float* __restrict__ x, const float* __restrict__ gain,
    u16* __restrict__ h) {
  const int row = blockIdx.x;
  const int tid = threadIdx.x;
  const float4 v = *(const float4*)(x + (long)row * 1024 + tid * 4);
  float s = fabsf(v.x) + fabsf(v.y) + fabsf(v.z) + fabsf(v.w);
  s = block_sum(s);
  const float scale = 1.0f / (s * (1.0f / 1024.0f) + EPSF);
  const float4 g = *(const float4*)(gain + tid * 4);
  ushort4 o;
  o.x = f2bf(v.x * g.x * scale);
  o.y = f2bf(v.y * g.y * scale);
  o.z = f2bf(v.z * g.z * scale);
  o.w = f2bf(v.w * g.w * scale);
  *(ushort4*)(h + (long)row * 1024 + tid * 4) = o;
}

// =====================================================================
// Attention v4 (unchanged, proven): register-resident S.
// =====================================================================
__global__ __launch_bounds__(512, 4) void attn_v4(
    const u16* __restrict__ qkv, const u16* __restrict__ v_t,
    u16* __restrict__ obuf, const float* __restrict__ score_gain, int l) {
  __shared__ float red1[2][4][16], red2[2][4][16], red3[2][4][16];
  __shared__ float Ured[2][4][16][68];
  __shared__ u16 Pl[8][640];
  const int qt = blockIdx.x, h = blockIdx.y, b = blockIdx.z;
  const int tid = threadIdx.x, w = tid >> 6, l64 = tid & 63;
  const int lq = l64 & 15, kgrp = l64 >> 4;
  const int wq = w >> 2, tq = w & 3;
  const int qglob = qt * 32 + wq * 16 + lq;
  const int qmax  = qt * 32 + wq * 16 + 15;
  const int tbase = tq * 256;
  const u16* Qg = qkv + (size_t)b * (1024 * 3072) + h * 64;
  const u16* Kg = Qg + 1024;
  const u16* Vt = v_t + (size_t)(b * 16 + h) * (64 * 1024);
  char* Pw = (char*)&Pl[w][0];

  bf16x8 qB0, qB1;
  {
    const u16* qp = Qg + (size_t)qglob * 3072 + (kgrp << 3);
    qB0 = *(const bf16x8*)qp;
    qB1 = *(const bf16x8*)(qp + 32);
  }

  f32x4 s[16];
  {
    const u16* Kl = Kg + (size_t)(tbase + lq) * 3072 + (kgrp << 3);
    #pragma unroll
    for (int tile = 0; tile < 16; tile++) {
      const u16* kp = Kl + (size_t)tile * (16 * 3072);
      const bf16x8 k0 = *(const bf16x8*)kp;
      const bf16x8 k1 = *(const bf16x8*)(kp + 32);
      f32x4 d = {0.f, 0.f, 0.f, 0.f};
      d = __builtin_amdgcn_mfma_f32_16x16x32_bf16(k0, qB0, d, 0, 0, 0);
      d = __builtin_amdgcn_mfma_f32_16x16x32_bf16(k1, qB1, d, 0, 0, 0);
      s[tile] = d;
    }
  }

  float ssum = 0.f;
  #pragma unroll
  for (int tile = 0; tile < 16; tile++)
    ssum += (s[tile][0] + s[tile][1]) + (s[tile][2] + s[tile][3]);
  ssum += __shfl_xor(ssum, 16, 64);
  ssum += __shfl_xor(ssum, 32, 64);
  if (l64 < 16) red1[wq][tq][l64] = ssum;
  __syncthreads();
  const float mean = (red1[wq][0][lq] + red1[wq][1][lq] +
                      red1[wq][2][lq] + red1[wq][3][lq]) * (1.0f / 1024.0f);

  float asum = 0.f;
  #pragma unroll
  for (int tile = 0; tile < 16; tile++)
    asum += fabsf(s[tile][0] - mean) + fabsf(s[tile][1] - mean) +
            fabsf(s[tile][2] - mean) + fabsf(s[tile][3] - mean);
  asum += __shfl_xor(asum, 16, 64);
  asum += __shfl_xor(asum, 32, 64);
  if (l64 < 16) red2[wq][tq][l64] = asum;
  __syncthreads();
  const float mad = (red2[wq][0][lq] + red2[wq][1][lq] +
                     red2[wq][2][lq] + red2[wq][3][lq]) * (1.0f / 1024.0f) + EPSF;
  const float gs = score_gain[l] / mad;

  float psum = 0.f;
  #pragma unroll
  for (int tile = 0; tile < 16; tile++) {
    #pragma unroll
    for (int j = 0; j < 4; j++) {
      const int t = tbase + tile * 16 + (kgrp << 2) + j;
      float sv = (s[tile][j] - mean) * gs;
      if (t > qglob) sv = -1000.0f;
      const float rr = sv / (fabsf(sv) + 1.0f);
      const float a1 = (rr + 1.0f) * 0.5f;
      const float a2 = a1 * a1;
      s[tile][j] = a2 * a2;
      psum += s[tile][j];
    }
  }

  f32x4 U[4] = {};
  #pragma unroll
  for (int c = 0; c < 8; c++) {
    const int t0 = tbase + c * 32;
    if (t0 <= qmax) {
      #pragma unroll
      for (int half = 0; half < 2; half++) {
        #pragma unroll
        for (int pr = 0; pr < 2; pr++) {
          const u32 pk = (u32)f2bf(s[2 * c + half][pr * 2]) |
                         ((u32)f2bf(s[2 * c + half][pr * 2 + 1]) << 16);
          *(u32*)(Pw + lq * 80 + half * 32 + (kgrp << 3) + (pr << 2)) = pk;
        }
      }
      asm volatile("s_waitcnt lgkmcnt(0)" ::: "memory");
      __builtin_amdgcn_sched_barrier(0);
      const bf16x8 pB = *(const bf16x8*)(Pw + lq * 80 + (kgrp << 4));
      #pragma unroll
      for (int dt = 0; dt < 4; dt++) {
        const bf16x8 vA = *(const bf16x8*)(Vt + (size_t)((dt << 4) + lq) * 1024 +
                                           t0 + (kgrp << 3));
        U[dt] = __builtin_amdgcn_mfma_f32_16x16x32_bf16(vA, pB, U[dt], 0, 0, 0);
      }
    }
  }

  psum += __shfl_xor(psum, 16, 64);
  psum += __shfl_xor(psum, 32, 64);
  if (l64 < 16) red3[wq][tq][l64] = psum;
  #pragma unroll
  for (int dt = 0; dt < 4; dt++)
    *(float4*)&Ured[wq][tq][lq][(dt << 4) + (kgrp << 2)] = *(const float4*)&U[dt];
  __syncthreads();

  {
    const int qq = tid >> 4, dhseg = (tid & 15) << 2;
    const int fwq = qq >> 4, flq = qq & 15;
    const float fps = red3[fwq][0][flq] + red3[fwq][1][flq] +
                      red3[fwq][2][flq] + red3[fwq][3][flq];
    const float oinv = 1.0f / (fps + EPSF);
    float4 u0 = *(const float4*)&Ured[fwq][0][flq][dhseg];
    const float4 u1 = *(const float4*)&Ured[fwq][1][flq][dhseg];
    const float4 u2 = *(const float4*)&Ured[fwq][2][flq][dhseg];
    const float4 u3 = *(const float4*)&Ured[fwq][3][flq][dhseg];
    u0.x = (u0.x + u1.x + u2.x + u3.x) * oinv;
    u0.y = (u0.y + u1.y + u2.y + u3.y) * oinv;
    u0.z = (u0.z + u1.z + u2.z + u3.z) * oinv;
    u0.w = (u0.w + u1.w + u2.w + u3.w) * oinv;
    ushort4 o;
    o.x = f2bf(u0.x); o.y = f2bf(u0.y); o.z = f2bf(u0.z); o.w = f2bf(u0.w);
    u16* dst = obuf + ((size_t)((b << 10) + qt * 32 + qq) << 10) + (h << 6) + dhseg;
    *(ushort4*)dst = o;
  }
}

// ---------------- weight conversion v3: 64x64 tiles, ONE dispatch ----------------
// float4 global reads (16B/lane), ushort4 global writes (8B/lane);
// LDS [64][65] scalar both phases (2-way banks, free).
__global__ void wconv_all(
    const float* __restrict__ Wq, const float* __restrict__ Wk,
    const float* __restrict__ Wv, const float* __restrict__ Wo,
    const float* __restrict__ W1, const float* __restrict__ W2,
    const float* __restrict__ Wlm,
    u16* __restrict__ wqkv_t, u16* __restrict__ wo_t,
    u16* __restrict__ w1_t, u16* __restrict__ w2_t, u16* __restrict__ wlm_t) {
  __shared__ float tile[64][65];
  const int bid = blockIdx.x;
  const float* src; u16* dst; int R, C, c0, r0;
  if (bid < 4096) {
    const int l = bid >> 10, m = (bid >> 8) & 3, t = bid & 255;
    if (m == 0)      src = Wq + (size_t)l * 1048576;
    else if (m == 1) src = Wk + (size_t)l * 1048576;
    else if (m == 2) src = Wv + (size_t)l * 1048576;
    else             src = Wo + (size_t)l * 1048576;
    dst = (m < 3) ? wqkv_t + ((size_t)l * 3072 + m * 1024) * 1024
                  : wo_t + (size_t)l * 1048576;
    R = 1024; C = 1024; c0 = (t & 15) << 6; r0 = (t >> 4) << 6;
  } else if (bid < 8192) {
    const int i = bid - 4096, l = i >> 10, t = i & 1023;
    src = W1 + (size_t)l * 4194304; dst = w1_t + (size_t)l * 4194304;
    R = 1024; C = 4096; c0 = (t & 63) << 6; r0 = (t >> 6) << 6;
  } else if (bid < 12288) {
    const int i = bid - 8192, l = i >> 10, t = i & 1023;
    src = W2 + (size_t)l * 4194304; dst = w2_t + (size_t)l * 4194304;
    R = 4096; C = 1024; c0 = (t & 15) << 6; r0 = (t >> 4) << 6;
  } else {
    const int i = bid - 12288;
    src = Wlm; dst = wlm_t;
    R = 1024; C = 32000; c0 = (i % 500) << 6; r0 = (i / 500) << 6;
  }
  const int tx = threadIdx.x, ty = threadIdx.y;   // (64,4)
  const int cg = (tx & 15) << 2;                  // 4-col group
  const int rg = tx >> 4;                         // row sub 0..3
  #pragma unroll
  for (int i = 0; i < 4; i++) {
    const int row = i * 16 + ty * 4 + rg;
    const float4 v = *(const float4*)&src[(long)(r0 + row) * C + c0 + cg];
    tile[row][cg] = v.x; tile[row][cg + 1] = v.y;
    tile[row][cg + 2] = v.z; tile[row][cg + 3] = v.w;
  }
  __syncthreads();
  #pragma unroll
  for (int i = 0; i < 4; i++) {
    const int c = i * 16 + ty * 4 + rg;           // output row = source col
    ushort4 o;
    o.x = f2bf(tile[cg][c]);     o.y = f2bf(tile[cg + 1][c]);
    o.z = f2bf(tile[cg + 2][c]); o.w = f2bf(tile[cg + 3][c]);
    *(ushort4*)&dst[(long)(c0 + c) * R + r0 + cg] = o;
  }
}

__global__ __launch_bounds__(256) void bias_concat(
    const float* __restrict__ bq, const float* __restrict__ bk,
    const float* __restrict__ bv, float* __restrict__ out) {
  const int i = blockIdx.x * 256 + threadIdx.x;
  const int l = i / 3072, j = i % 3072;
  float v;
  if (j < 1024)      v = bq[l * 1024 + j];
  else if (j < 2048) v = bk[l * 1024 + j - 1024];
  else               v = bv[l * 1024 + j - 2048];
  out[i] = v;
}

// ---- FFN2 split-K=4 reduce + residual + anorm(next gain) fused ----
__global__ __launch_bounds__(256) void ffn2_reduce_norm(
    const float* __restrict__ part, const float* __restrict__ b2,
    float* __restrict__ x, const float* __restrict__ gain,
    u16* __restrict__ h) {
  const int row = blockIdx.x, c = threadIdx.x * 4;
  const float4 p0 = *(const float4*)(part + (size_t)row * 1024 + c);
  const float4 p1 = *(const float4*)(part + (size_t)(row + 2048) * 1024 + c);
  const float4 p2 = *(const float4*)(part + (size_t)(row + 4096) * 1024 + c);
  const float4 p3 = *(const float4*)(part + (size_t)(row + 6144) * 1024 + c);
  const float4 bb = *(const float4*)(b2 + c);
  float4 xv = *(float4*)(x + (size_t)row * 1024 + c);
  xv.x += (p0.x + p1.x) + (p2.x + p3.x) + bb.x;
  xv.y += (p0.y + p1.y) + (p2.y + p3.y) + bb.y;
  xv.z += (p0.z + p1.z) + (p2.z + p3.z) + bb.z;
  xv.w += (p0.w + p1.w) + (p2.w + p3.w) + bb.w;
  *(float4*)(x + (size_t)row * 1024 + c) = xv;
  float s = fabsf(xv.x) + fabsf(xv.y) + fabsf(xv.z) + fabsf(xv.w);
  s = block_sum(s);
  const float scale = 1.0f / (s * (1.0f / 1024.0f) + EPSF);
  const float4 g = *(const float4*)(gain + c);
  ushort4 o;
  o.x = f2bf(xv.x * g.x * scale);
  o.y = f2bf(xv.y * g.y * scale);
  o.z = f2bf(xv.z * g.z * scale);
  o.w = f2bf(xv.w * g.w * scale);
  *(ushort4*)(h + (size_t)row * 1024 + c) = o;
}

// =====================================================================
// 256x256-tile deep-pipelined GEMM (round-7 proven version, 158-160 µs LM)
// =====================================================================
template <bool OUT_BF16, bool BIAS, bool RELU, bool RESID>
__global__ __launch_bounds__(512) void gemm256_kernel(
    const u16* __restrict__ A, long lda,
    const u16* __restrict__ Bt, long ldb,
    void* __restrict__ Cv, long ldc,
    const float* __restrict__ bias, const float* __restrict__ resid,
    int M, int N, int K, int nTM) {
  __shared__ u16 lds[65536];
  const int nwg = gridDim.x;
  const int qx = nwg >> 3, rx = nwg & 7;
  const int xcd = blockIdx.x & 7, seq = blockIdx.x >> 3;
  const int wg = (xcd < rx ? xcd * (qx + 1) : rx * (qx + 1) + (xcd - rx) * qx) + seq;
  const int tm = wg % nTM, tn = wg / nTM;
  const int rowA0 = tm * 256, rowB0 = tn * 256;

  const int t = threadIdx.x, w = t >> 6, l = t & 63;
  const int lrow = l & 15, kgrp = l >> 4;
  const int wr = w >> 2, wc = w & 3;

  const int srow = t >> 2;
  const int scol = ((t & 3) ^ ((t >> 3) & 3)) * 8;
  const u16* Asrc = A + (long)(rowA0 + srow) * lda + scol;
  const u16* Bsrc = Bt + (long)(rowB0 + srow) * ldb + scol;
  char* ldsB = (char*)lds;
  const int wbase = w * 1024;

  const int fswz = (kgrp ^ ((lrow >> 1) & 3)) * 8;
  const int aoff = (wr * 128 + lrow) * 32 + fswz;
  const int boff = 8192 + (wc * 64 + lrow) * 32 + fswz;

  f32x4 acc[8][4] = {};
  const int NT = K >> 5;

  #pragma unroll
  for (int pt = 0; pt < 3; pt++) {
    const int k0 = pt << 5;
    const int bb = pt * 32768;
    lds_cp16(Asrc + k0,                    ldsB + bb + wbase);
    lds_cp16(Asrc + (long)128 * lda + k0,  ldsB + bb + 8192 + wbase);
    lds_cp16(Bsrc + k0,                    ldsB + bb + 16384 + wbase);
    lds_cp16(Bsrc + (long)128 * ldb + k0,  ldsB + bb + 24576 + wbase);
  }

  for (int tt = 0; tt < NT; tt++) {
    const int rem = NT - 1 - tt;
    if (rem >= 2)      asm volatile("s_waitcnt vmcnt(8)" ::: "memory");
    else if (rem == 1) asm volatile("s_waitcnt vmcnt(4)" ::: "memory");
    else               asm volatile("s_waitcnt vmcnt(0)" ::: "memory");
    __builtin_amdgcn_sched_barrier(0);
    __builtin_amdgcn_s_barrier();

    const u16* buf = lds + (tt & 3) * 16384;
    const int stage = tt + 3 < NT;
    const int k0n = (tt + 3) << 5;
    const int bbn = ((tt + 3) & 3) * 32768;

    bf16x8 aF[4], bF[4];
    #pragma unroll
    for (int m = 0; m < 4; m++) aF[m] = *(const bf16x8*)(buf + aoff + m * 512);
    #pragma unroll
    for (int n = 0; n < 4; n++) bF[n] = *(const bf16x8*)(buf + boff + n * 512);
    if (stage) {
      lds_cp16(Asrc + k0n,                   ldsB + bbn + wbase);
      lds_cp16(Asrc + (long)128 * lda + k0n, ldsB + bbn + 8192 + wbase);
    }
    asm volatile("s_waitcnt lgkmcnt(0)" ::: "memory");
    __builtin_amdgcn_sched_barrier(0);
    __builtin_amdgcn_s_setprio(1);
    #pragma unroll
    for (int m = 0; m < 4; m++)
      #pragma unroll
      for (int n = 0; n < 4; n++)
        acc[m][n] = __builtin_amdgcn_mfma_f32_16x16x32_bf16(aF[m], bF[n], acc[m][n], 0, 0, 0);
    __builtin_amdgcn_s_setprio(0);

    #pragma unroll
    for (int m = 0; m < 4; m++) aF[m] = *(const bf16x8*)(buf + aoff + (m + 4) * 512);
    if (stage) {
      lds_cp16(Bsrc + k0n,                   ldsB + bbn + 16384 + wbase);
      lds_cp16(Bsrc + (long)128 * ldb + k0n, ldsB + bbn + 24576 + wbase);
    }
    asm volatile("s_waitcnt lgkmcnt(0)" ::: "memory");
    __builtin_amdgcn_sched_barrier(0);
    __builtin_amdgcn_s_setprio(1);
    #pragma unroll
    for (int m = 0; m < 4; m++)
      #pragma unroll
      for (int n = 0; n < 4; n++)
        acc[m + 4][n] = __builtin_amdgcn_mfma_f32_16x16x32_bf16(aF[m], bF[n], acc[m + 4][n], 0, 0, 0);
    __builtin_amdgcn_s_setprio(0);
  }

  float bvv[4];
  #pragma unroll
  for (int n = 0; n < 4; n++)
    bvv[n] = BIAS ? bias[rowB0 + wc * 64 + n * 16 + lrow] : 0.0f;
  #pragma unroll
  for (int m = 0; m < 8; m++) {
    const int row = rowA0 + wr * 128 + m * 16 + kgrp * 4;
    #pragma unroll
    for (int n = 0; n < 4; n++) {
      const int col = rowB0 + wc * 64 + n * 16 + lrow;
      #pragma unroll
      for (int j = 0; j < 4; j++) {
        float v = acc[m][n][j] + bvv[n];
        if (RELU) v = fmaxf(v, 0.0f);
        const long off = (long)(row + j) * ldc + col;
        if (RESID) v += resid[off];
        if (OUT_BF16) ((u16*)Cv)[off] = f2bf(v);
        else          ((float*)Cv)[off] = v;
      }
    }
  }
}

// =====================================================================
// 128x128-tile pipelined GEMM (proven): 4 waves, BK=32, 4-deep ring,
// 2 blocks/CU, counted vmcnt, swizzled. VTOUT transposes V-tiles to v_t.
// =====================================================================
template <bool OUT_BF16, bool BIAS, bool RELU, bool RESID, bool VTOUT>
__global__ __launch_bounds__(256) void gemm128p(
    const u16* __restrict__ A, long lda, long sA,
    const u16* __restrict__ Bt, long ldb, long sB,
    void* __restrict__ Cv, long ldc, long sC,
    const float* __restrict__ bias, const float* __restrict__ resid,
    u16* __restrict__ vtout,
    int M, int N, int K, int nTM) {
  __shared__ u16 lds[32768];
  const int nwg = gridDim.x;
  const int qx = nwg >> 3, rx = nwg & 7;
  const int xcd = blockIdx.x & 7, seq = blockIdx.x >> 3;
  const int wg = (xcd < rx ? xcd * (qx + 1) : rx * (qx + 1) + (xcd - rx) * qx) + seq;
  const int tm = wg % nTM, tn = wg / nTM;
  const int batch = blockIdx.y;
  A  += (long)batch * sA;
  Bt += (long)batch * sB;
  const int rowA0 = tm * 128, rowB0 = tn * 128;
  const int t = threadIdx.x, w = t >> 6, l = t & 63;
  const int lrow = l & 15, kgrp = l >> 4;
  const int wr = (w >> 1) << 6, wc = (w & 1) << 6;

  const int srow = t >> 2;
  const int scol = ((t & 3) ^ ((t >> 3) & 3)) * 8;
  const u16* Asrc = A + (long)(rowA0 + srow) * lda + scol;
  const u16* Bsrc = Bt + (long)(rowB0 + srow) * ldb + scol;
  char* ldsB = (char*)lds;
  const int wbase = w * 1024;

  const int swz8 = (kgrp ^ ((lrow >> 1) & 3)) * 8;
  const int aoff = (wr + lrow) * 32 + swz8;
  const int boff = 4096 + (wc + lrow) * 32 + swz8;

  f32x4 acc[4][4] = {};
  const int NT = K >> 5;

  #pragma unroll
  for (int pt = 0; pt < 3; pt++) {
    const int k0 = pt << 5;
    const int bb = pt * 16384;
    lds_cp16(Asrc + k0,                   ldsB + bb + wbase);
    lds_cp16(Asrc + (long)64 * lda + k0,  ldsB + bb + 4096 + wbase);
    lds_cp16(Bsrc + k0,                   ldsB + bb + 8192 + wbase);
    lds_cp16(Bsrc + (long)64 * ldb + k0,  ldsB + bb + 12288 + wbase);
  }

  for (int tt = 0; tt < NT; tt++) {
    const int rem = NT - 1 - tt;
    if (rem >= 2)      asm volatile("s_waitcnt vmcnt(8)" ::: "memory");
    else if (rem == 1) asm volatile("s_waitcnt vmcnt(4)" ::: "memory");
    else               asm volatile("s_waitcnt vmcnt(0)" ::: "memory");
    __builtin_amdgcn_sched_barrier(0);
    __builtin_amdgcn_s_barrier();

    const u16* buf = lds + (tt & 3) * 8192;
    const int stage = tt + 3 < NT;
    const int k0n = (tt + 3) << 5;
    const int bbn = ((tt + 3) & 3) * 16384;

    bf16x8 aF[4], bF[4];
    #pragma unroll
    for (int m = 0; m < 4; m++) aF[m] = *(const bf16x8*)(buf + aoff + m * 512);
    #pragma unroll
    for (int n = 0; n < 4; n++) bF[n] = *(const bf16x8*)(buf + boff + n * 512);
    if (stage) {
      lds_cp16(Asrc + k0n,                  ldsB + bbn + wbase);
      lds_cp16(Asrc + (long)64 * lda + k0n, ldsB + bbn + 4096 + wbase);
      lds_cp16(Bsrc + k0n,                  ldsB + bbn + 8192 + wbase);
      lds_cp16(Bsrc + (long)64 * ldb + k0n, ldsB + bbn + 12288 + wbase);
    }
    asm volatile("s_waitcnt lgkmcnt(0)" ::: "memory");
    __builtin_amdgcn_sched_barrier(0);
    __builtin_amdgcn_s_setprio(1);
    #pragma unroll
    for (int m = 0; m < 4; m++)
      #pragma unroll
      for (int n = 0; n < 4; n++)
        acc[m][n] = __builtin_amdgcn_mfma_f32_16x16x32_bf16(aF[m], bF[n], acc[m][n], 0, 0, 0);
    __builtin_amdgcn_s_setprio(0);
  }

  if (VTOUT && rowB0 >= 2048) {
    __syncthreads();
    #pragma unroll
    for (int m = 0; m < 4; m++) {
      #pragma unroll
      for (int n = 0; n < 4; n++) {
        const int c = wc + n * 16 + lrow;
        const int r = wr + m * 16 + (kgrp << 2);
        ushort4 pk;
        float v0 = acc[m][n][0], v1 = acc[m][n][1], v2 = acc[m][n][2], v3 = acc[m][n][3];
        if (BIAS) {
          const float bv = bias[rowB0 + c];
          v0 += bv; v1 += bv; v2 += bv; v3 += bv;
        }
        pk.x = f2bf(v0); pk.y = f2bf(v1); pk.z = f2bf(v2); pk.w = f2bf(v3);
        *(ushort4*)&lds[c * 136 + r] = pk;
      }
    }
    __syncthreads();
    {
      const int c = t >> 1, half = t & 1;
      const int dh = c & 63;
      const int h = ((rowB0 - 2048) >> 6) + (c >> 6);
      const int bb2 = rowA0 >> 10, t0 = rowA0 & 1023;
      u16* dst = vtout + (((size_t)(bb2 * 16 + h)) << 16) + ((size_t)dh << 10) +
                 t0 + half * 64;
      #pragma unroll
      for (int k = 0; k < 8; k++)
        *(bf16x8*)(dst + k * 8) = *(const bf16x8*)&lds[c * 136 + half * 64 + k * 8];
    }
  } else {
    const long coff = (long)batch * sC;
    #pragma unroll
    for (int m = 0; m < 4; m++) {
      #pragma unroll
      for (int n = 0; n < 4; n++) {
        const int col = rowB0 + wc + n * 16 + lrow;
        #pragma unroll
        for (int j = 0; j < 4; j++) {
          const int row = rowA0 + wr + m * 16 + (kgrp << 2) + j;
          float v = acc[m][n][j];
          if (BIAS) v += bias[col];
          if (RELU) v = fmaxf(v, 0.0f);
          const long off = coff + (long)row * ldc + col;
          if (RESID) v += resid[off];
          if (OUT_BF16) ((u16*)Cv)[off] = f2bf(v);
          else          ((float*)Cv)[off] = v;
        }
      }
    }
  }
}

extern "C" void kernel_launch(void* const* d_in, const int* in_sizes, int n_in,
                              void* d_out, int out_size, void* d_ws, size_t ws_size,
                              hipStream_t stream) {
  constexpr int Lc = 4, Tc = 1024, Dc = 1024, Hc = 16, Fc = 4096, DHc = 64;
  const int M = 2 * Tc;

  const int*   idxp       = (const int*)  d_in[0];
  const float* tok_emb    = (const float*)d_in[1];
  const float* pos_emb    = (const float*)d_in[2];
  const float* Wq         = (const float*)d_in[3];
  const float* bq         = (const float*)d_in[4];
  const float* Wk         = (const float*)d_in[5];
  const float* bk         = (const float*)d_in[6];
  const float* Wv         = (const float*)d_in[7];
  const float* bv         = (const float*)d_in[8];
  const float* Wo         = (const float*)d_in[9];
  const float* bo         = (const float*)d_in[10];
  const float* score_gain = (const float*)d_in[11];
  const float* norm1_gain = (const float*)d_in[12];
  const float* norm2_gain = (const float*)d_in[13];
  const float* W1         = (const float*)d_in[14];
  const float* b1         = (const float*)d_in[15];
  const float* W2         = (const float*)d_in[16];
  const float* b2         = (const float*)d_in[17];
  const float* final_gain = (const float*)d_in[18];
  const float* Wlm        = (const float*)d_in[19];
  const float* blm        = (const float*)d_in[20];

  char* p = (char*)d_ws;
  auto alloc = [&](size_t n) { char* r = p; p += (n + 255) & ~(size_t)255; return r; };
  u16*  wqkv_t = (u16*) alloc((size_t)Lc * 3072 * 1024 * 2);
  u16*  wo_t   = (u16*) alloc((size_t)Lc * 1024 * 1024 * 2);
  u16*  w1_t   = (u16*) alloc((size_t)Lc * 4096 * 1024 * 2);
  u16*  w2_t   = (u16*) alloc((size_t)Lc * 1024 * 4096 * 2);
  u16*  wlm_t  = (u16*) alloc((size_t)32000 * 1024 * 2);
  float* bqkv  = (float*)alloc((size_t)Lc * 3072 * 4);
  float* x     = (float*)alloc((size_t)M * 1024 * 4);
  u16*  hbuf   = (u16*) alloc((size_t)M * 1024 * 2);
  u16*  qkv    = (u16*) alloc((size_t)M * 3072 * 2);
  u16*  v_t    = (u16*) alloc((size_t)2 * Hc * DHc * Tc * 2);
  u16*  obuf   = (u16*) alloc((size_t)M * 1024 * 2);
  u16*  ffh    = (u16*) alloc((size_t)M * 4096 * 2);
  float* fpart = (float*)alloc((size_t)4 * M * 1024 * 4);

  wconv_all<<<20288, dim3(64, 4), 0, stream>>>(Wq, Wk, Wv, Wo, W1, W2, Wlm,
                                               wqkv_t, wo_t, w1_t, w2_t, wlm_t);
  bias_concat<<<48, 256, 0, stream>>>(bq, bk, bv, bqkv);
  embed_norm<<<M, 256, 0, stream>>>(idxp, tok_emb, pos_emb, norm1_gain, x, hbuf);

  for (int l = 0; l < Lc; l++) {
    // QKV (V columns transposed straight into v_t via LDS epilogue)
    gemm128p<true, true, false, false, true><<<dim3(16 * 24, 1), 256, 0, stream>>>(
        hbuf, 1024, 0, wqkv_t + (size_t)l * 3072 * 1024, 1024, 0,
        qkv, 3072, 0, bqkv + (size_t)l * 3072, nullptr, v_t, M, 3072, 1024, 16);

    attn_v4<<<dim3(32, 16, 2), 512, 0, stream>>>(qkv, v_t, obuf, score_gain, l);

    gemm128p<false, true, false, true, false><<<dim3(16 * 8, 1), 256, 0, stream>>>(
        obuf, 1024, 0, wo_t + (size_t)l * 1024 * 1024, 1024, 0,
        x, 1024, 0, bo + (size_t)l * 1024, x, nullptr, M, 1024, 1024, 16);
    anorm_kernel<<<M, 256, 0, stream>>>(x, norm2_gain + (size_t)l * Dc, hbuf);
    gemm128p<true, true, true, false, false><<<dim3(16 * 32, 1), 256, 0, stream>>>(
        hbuf, 1024, 0, w1_t + (size_t)l * Fc * Dc, 1024, 0,
        ffh, 4096, 0, b1 + (size_t)l * Fc, nullptr, nullptr, M, 4096, 1024, 16);
    gemm128p<false, false, false, false, false><<<dim3(128, 4), 256, 0, stream>>>(
        ffh, 4096, 1024, w2_t + (size_t)l * Dc * Fc, 4096, 1024,
        fpart, 1024, (long)M * 1024, nullptr, nullptr, nullptr, M, 1024, 1024, 16);
    const float* gnext = (l < Lc - 1) ? (norm1_gain + (size_t)(l + 1) * Dc) : final_gain;
    ffn2_reduce_norm<<<M, 256, 0, stream>>>(fpart, b2 + (size_t)l * Dc, x, gnext, hbuf);
  }

  // LM head back on gemm256: grid 1000, 16 B/output tile efficiency
  gemm256_kernel<false, true, false, false><<<dim3(1000), 512, 0, stream>>>(
      hbuf, 1024, wlm_t, 1024,
      d_out, 32000, blm, nullptr, M, 32000, 1024, 8);
}

// Round 11
// 978.690 us; speedup vs baseline: 1.0438x; 1.0125x over previous
//
#include <hip/hip_runtime.h>

typedef unsigned short u16;
typedef __bf16 bf16x8 __attribute__((ext_vector_type(8)));
typedef float f32x4 __attribute__((ext_vector_type(4)));
typedef unsigned int u32;

#define EPSF 1e-6f

__device__ __forceinline__ u16 f2bf(float f) {
  union { float f; unsigned u; } un; un.f = f;
  unsigned r = un.u + 0x7FFFu + ((un.u >> 16) & 1u);
  return (u16)(r >> 16);
}

__device__ __forceinline__ float block_sum(float v) {
  #pragma unroll
  for (int off = 32; off > 0; off >>= 1) v += __shfl_xor(v, off, 64);
  __shared__ float ws[4];
  const int w = threadIdx.x >> 6;
  __syncthreads();
  if ((threadIdx.x & 63) == 0) ws[w] = v;
  __syncthreads();
  return ws[0] + ws[1] + ws[2] + ws[3];
}

// async global->LDS, 16B per lane. LDS dest must be wave-uniform base; HW adds lane*16.
__device__ __forceinline__ void lds_cp16(const void* g, void* l) {
  __builtin_amdgcn_global_load_lds(
      (__attribute__((address_space(1))) void*)g,
      (__attribute__((address_space(3))) void*)l, 16, 0, 0);
}

// ---------------- embedding + anorm(norm1_gain[0]) fused ----------------
__global__ __launch_bounds__(256) void embed_norm(
    const int* __restrict__ idx, const float* __restrict__ tok,
    const float* __restrict__ pos, const float* __restrict__ gain,
    float* __restrict__ x, u16* __restrict__ h) {
  const int row = blockIdx.x;
  const int tpos = row & 1023;
  const int token = idx[row];
  const int d = threadIdx.x * 4;
  const float4 a = *(const float4*)(tok + (long)token * 1024 + d);
  const float4 b = *(const float4*)(pos + (long)tpos * 1024 + d);
  float4 o; o.x = a.x + b.x; o.y = a.y + b.y; o.z = a.z + b.z; o.w = a.w + b.w;
  *(float4*)(x + (long)row * 1024 + d) = o;
  float s = fabsf(o.x) + fabsf(o.y) + fabsf(o.z) + fabsf(o.w);
  s = block_sum(s);
  const float scale = 1.0f / (s * (1.0f / 1024.0f) + EPSF);
  const float4 g = *(const float4*)(gain + d);
  ushort4 ov;
  ov.x = f2bf(o.x * g.x * scale);
  ov.y = f2bf(o.y * g.y * scale);
  ov.z = f2bf(o.z * g.z * scale);
  ov.w = f2bf(o.w * g.w * scale);
  *(ushort4*)(h + (long)row * 1024 + d) = ov;
}

// =====================================================================
// Attention v5: register-resident S with INTERLEAVED causal ownership.
// Wave (wq,tq): chunk cc covers global t-chunk g = cc*4 + tq (stride-4),
// so PV causal work is balanced across the 4 tq-waves for every q-tile.
// V fragment loads hoisted above the p LDS bounce (latency overlap).
// =====================================================================
__global__ __launch_bounds__(512, 4) void attn_v5(
    const u16* __restrict__ qkv, const u16* __restrict__ v_t,
    u16* __restrict__ obuf, const float* __restrict__ score_gain, int l) {
  __shared__ float red1[2][4][16], red2[2][4][16], red3[2][4][16];
  __shared__ float Ured[2][4][16][68];
  __shared__ u16 Pl[8][640];
  const int qt = blockIdx.x, h = blockIdx.y, b = blockIdx.z;
  const int tid = threadIdx.x, w = tid >> 6, l64 = tid & 63;
  const int lq = l64 & 15, kgrp = l64 >> 4;
  const int wq = w >> 2, tq = w & 3;
  const int qglob = qt * 32 + wq * 16 + lq;
  const int qmax  = qt * 32 + wq * 16 + 15;
  const u16* Qg = qkv + (size_t)b * (1024 * 3072) + h * 64;
  const u16* Kg = Qg + 1024;
  const u16* Vt = v_t + (size_t)(b * 16 + h) * (64 * 1024);
  char* Pw = (char*)&Pl[w][0];

  bf16x8 qB0, qB1;
  {
    const u16* qp = Qg + (size_t)qglob * 3072 + (kgrp << 3);
    qB0 = *(const bf16x8*)qp;
    qB1 = *(const bf16x8*)(qp + 32);
  }

  // ---- QK^T: tile tl covers t rows tq*32 + (tl>>1)*128 + (tl&1)*16 ----
  f32x4 s[16];
  {
    const u16* Ktq = Kg + (size_t)(tq * 32 + lq) * 3072 + (kgrp << 3);
    #pragma unroll
    for (int tl = 0; tl < 16; tl++) {
      const int cst = ((tl >> 1) << 7) + ((tl & 1) << 4);   // compile-time
      const u16* kp = Ktq + (size_t)cst * 3072;
      const bf16x8 k0 = *(const bf16x8*)kp;
      const bf16x8 k1 = *(const bf16x8*)(kp + 32);
      f32x4 d = {0.f, 0.f, 0.f, 0.f};
      d = __builtin_amdgcn_mfma_f32_16x16x32_bf16(k0, qB0, d, 0, 0, 0);
      d = __builtin_amdgcn_mfma_f32_16x16x32_bf16(k1, qB1, d, 0, 0, 0);
      s[tl] = d;
    }
  }

  // ---- stats (pre-mask, full row) ----
  float ssum = 0.f;
  #pragma unroll
  for (int tl = 0; tl < 16; tl++)
    ssum += (s[tl][0] + s[tl][1]) + (s[tl][2] + s[tl][3]);
  ssum += __shfl_xor(ssum, 16, 64);
  ssum += __shfl_xor(ssum, 32, 64);
  if (l64 < 16) red1[wq][tq][l64] = ssum;
  __syncthreads();
  const float mean = (red1[wq][0][lq] + red1[wq][1][lq] +
                      red1[wq][2][lq] + red1[wq][3][lq]) * (1.0f / 1024.0f);

  float asum = 0.f;
  #pragma unroll
  for (int tl = 0; tl < 16; tl++)
    asum += fabsf(s[tl][0] - mean) + fabsf(s[tl][1] - mean) +
            fabsf(s[tl][2] - mean) + fabsf(s[tl][3] - mean);
  asum += __shfl_xor(asum, 16, 64);
  asum += __shfl_xor(asum, 32, 64);
  if (l64 < 16) red2[wq][tq][l64] = asum;
  __syncthreads();
  const float mad = (red2[wq][0][lq] + red2[wq][1][lq] +
                     red2[wq][2][lq] + red2[wq][3][lq]) * (1.0f / 1024.0f) + EPSF;
  const float gs = score_gain[l] / mad;

  // ---- p in place, psum deferred ----
  float psum = 0.f;
  #pragma unroll
  for (int tl = 0; tl < 16; tl++) {
    const int tbase = tq * 32 + ((tl >> 1) << 7) + ((tl & 1) << 4);
    #pragma unroll
    for (int j = 0; j < 4; j++) {
      const int t = tbase + (kgrp << 2) + j;
      float sv = (s[tl][j] - mean) * gs;
      if (t > qglob) sv = -1000.0f;
      const float rr = sv / (fabsf(sv) + 1.0f);
      const float a1 = (rr + 1.0f) * 0.5f;
      const float a2 = a1 * a1;
      s[tl][j] = a2 * a2;
      psum += s[tl][j];
    }
  }

  // ---- PV: chunk cc -> t0 = tq*32 + cc*128 (interleaved, balanced) ----
  f32x4 U[4] = {};
  {
    const u16* Vtq = Vt + (size_t)lq * 1024 + tq * 32 + (kgrp << 3);
    #pragma unroll
    for (int cc = 0; cc < 8; cc++) {
      const int t0 = tq * 32 + (cc << 7);
      if (t0 <= qmax) {
        // V fragments first: global latency overlaps the LDS bounce below
        bf16x8 vA[4];
        #pragma unroll
        for (int dt = 0; dt < 4; dt++)
          vA[dt] = *(const bf16x8*)(Vtq + (size_t)(dt << 4) * 1024 + (cc << 7));
        #pragma unroll
        for (int half = 0; half < 2; half++) {
          #pragma unroll
          for (int pr = 0; pr < 2; pr++) {
            const u32 pk = (u32)f2bf(s[2 * cc + half][pr * 2]) |
                           ((u32)f2bf(s[2 * cc + half][pr * 2 + 1]) << 16);
            *(u32*)(Pw + lq * 80 + half * 32 + (kgrp << 3) + (pr << 2)) = pk;
          }
        }
        asm volatile("s_waitcnt lgkmcnt(0)" ::: "memory");
        __builtin_amdgcn_sched_barrier(0);
        const bf16x8 pB = *(const bf16x8*)(Pw + lq * 80 + (kgrp << 4));
        #pragma unroll
        for (int dt = 0; dt < 4; dt++)
          U[dt] = __builtin_amdgcn_mfma_f32_16x16x32_bf16(vA[dt], pB, U[dt], 0, 0, 0);
      }
    }
  }

  psum += __shfl_xor(psum, 16, 64);
  psum += __shfl_xor(psum, 32, 64);
  if (l64 < 16) red3[wq][tq][l64] = psum;
  #pragma unroll
  for (int dt = 0; dt < 4; dt++)
    *(float4*)&Ured[wq][tq][lq][(dt << 4) + (kgrp << 2)] = *(const float4*)&U[dt];
  __syncthreads();

  {
    const int qq = tid >> 4, dhseg = (tid & 15) << 2;
    const int fwq = qq >> 4, flq = qq & 15;
    const float fps = red3[fwq][0][flq] + red3[fwq][1][flq] +
                      red3[fwq][2][flq] + red3[fwq][3][flq];
    const float oinv = 1.0f / (fps + EPSF);
    float4 u0 = *(const float4*)&Ured[fwq][0][flq][dhseg];
    const float4 u1 = *(const float4*)&Ured[fwq][1][flq][dhseg];
    const float4 u2 = *(const float4*)&Ured[fwq][2][flq][dhseg];
    const float4 u3 = *(const float4*)&Ured[fwq][3][flq][dhseg];
    u0.x = (u0.x + u1.x + u2.x + u3.x) * oinv;
    u0.y = (u0.y + u1.y + u2.y + u3.y) * oinv;
    u0.z = (u0.z + u1.z + u2.z + u3.z) * oinv;
    u0.w = (u0.w + u1.w + u2.w + u3.w) * oinv;
    ushort4 o;
    o.x = f2bf(u0.x); o.y = f2bf(u0.y); o.z = f2bf(u0.z); o.w = f2bf(u0.w);
    u16* dst = obuf + ((size_t)((b << 10) + qt * 32 + qq) << 10) + (h << 6) + dhseg;
    *(ushort4*)dst = o;
  }
}

// ---------------- weight conversion v3 (proven): 64x64 tiles, ONE dispatch ----------------
__global__ void wconv_all(
    const float* __restrict__ Wq, const float* __restrict__ Wk,
    const float* __restrict__ Wv, const float* __restrict__ Wo,
    const float* __restrict__ W1, const float* __restrict__ W2,
    const float* __restrict__ Wlm,
    u16* __restrict__ wqkv_t, u16* __restrict__ wo_t,
    u16* __restrict__ w1_t, u16* __restrict__ w2_t, u16* __restrict__ wlm_t) {
  __shared__ float tile[64][65];
  const int bid = blockIdx.x;
  const float* src; u16* dst; int R, C, c0, r0;
  if (bid < 4096) {
    const int l = bid >> 10, m = (bid >> 8) & 3, t = bid & 255;
    if (m == 0)      src = Wq + (size_t)l * 1048576;
    else if (m == 1) src = Wk + (size_t)l * 1048576;
    else if (m == 2) src = Wv + (size_t)l * 1048576;
    else             src = Wo + (size_t)l * 1048576;
    dst = (m < 3) ? wqkv_t + ((size_t)l * 3072 + m * 1024) * 1024
                  : wo_t + (size_t)l * 1048576;
    R = 1024; C = 1024; c0 = (t & 15) << 6; r0 = (t >> 4) << 6;
  } else if (bid < 8192) {
    const int i = bid - 4096, l = i >> 10, t = i & 1023;
    src = W1 + (size_t)l * 4194304; dst = w1_t + (size_t)l * 4194304;
    R = 1024; C = 4096; c0 = (t & 63) << 6; r0 = (t >> 6) << 6;
  } else if (bid < 12288) {
    const int i = bid - 8192, l = i >> 10, t = i & 1023;
    src = W2 + (size_t)l * 4194304; dst = w2_t + (size_t)l * 4194304;
    R = 4096; C = 1024; c0 = (t & 15) << 6; r0 = (t >> 4) << 6;
  } else {
    const int i = bid - 12288;
    src = Wlm; dst = wlm_t;
    R = 1024; C = 32000; c0 = (i % 500) << 6; r0 = (i / 500) << 6;
  }
  const int tx = threadIdx.x, ty = threadIdx.y;   // (64,4)
  const int cg = (tx & 15) << 2;
  const int rg = tx >> 4;
  #pragma unroll
  for (int i = 0; i < 4; i++) {
    const int row = i * 16 + ty * 4 + rg;
    const float4 v = *(const float4*)&src[(long)(r0 + row) * C + c0 + cg];
    tile[row][cg] = v.x; tile[row][cg + 1] = v.y;
    tile[row][cg + 2] = v.z; tile[row][cg + 3] = v.w;
  }
  __syncthreads();
  #pragma unroll
  for (int i = 0; i < 4; i++) {
    const int c = i * 16 + ty * 4 + rg;
    ushort4 o;
    o.x = f2bf(tile[cg][c]);     o.y = f2bf(tile[cg + 1][c]);
    o.z = f2bf(tile[cg + 2][c]); o.w = f2bf(tile[cg + 3][c]);
    *(ushort4*)&dst[(long)(c0 + c) * R + r0 + cg] = o;
  }
}

__global__ __launch_bounds__(256) void bias_concat(
    const float* __restrict__ bq, const float* __restrict__ bk,
    const float* __restrict__ bv, float* __restrict__ out) {
  const int i = blockIdx.x * 256 + threadIdx.x;
  const int l = i / 3072, j = i % 3072;
  float v;
  if (j < 1024)      v = bq[l * 1024 + j];
  else if (j < 2048) v = bk[l * 1024 + j - 1024];
  else               v = bv[l * 1024 + j - 2048];
  out[i] = v;
}

// ---- split-K reduce + bias + residual + anorm(next gain) fused ----
template <int NPART>
__global__ __launch_bounds__(256) void reduce_norm(
    const float* __restrict__ part, const float* __restrict__ bias,
    float* __restrict__ x, const float* __restrict__ gain,
    u16* __restrict__ h) {
  const int row = blockIdx.x, c = threadIdx.x * 4;
  float4 acc = *(const float4*)(part + (size_t)row * 1024 + c);
  #pragma unroll
  for (int i = 1; i < NPART; i++) {
    const float4 pi = *(const float4*)(part + (size_t)(row + i * 2048) * 1024 + c);
    acc.x += pi.x; acc.y += pi.y; acc.z += pi.z; acc.w += pi.w;
  }
  const float4 bb = *(const float4*)(bias + c);
  float4 xv = *(float4*)(x + (size_t)row * 1024 + c);
  xv.x += acc.x + bb.x;
  xv.y += acc.y + bb.y;
  xv.z += acc.z + bb.z;
  xv.w += acc.w + bb.w;
  *(float4*)(x + (size_t)row * 1024 + c) = xv;
  float s = fabsf(xv.x) + fabsf(xv.y) + fabsf(xv.z) + fabsf(xv.w);
  s = block_sum(s);
  const float scale = 1.0f / (s * (1.0f / 1024.0f) + EPSF);
  const float4 g = *(const float4*)(gain + c);
  ushort4 o;
  o.x = f2bf(xv.x * g.x * scale);
  o.y = f2bf(xv.y * g.y * scale);
  o.z = f2bf(xv.z * g.z * scale);
  o.w = f2bf(xv.w * g.w * scale);
  *(ushort4*)(h + (size_t)row * 1024 + c) = o;
}

// =====================================================================
// 256x256-tile deep-pipelined GEMM (round-7 proven, used for LM head)
// =====================================================================
template <bool OUT_BF16, bool BIAS, bool RELU, bool RESID>
__global__ __launch_bounds__(512) void gemm256_kernel(
    const u16* __restrict__ A, long lda,
    const u16* __restrict__ Bt, long ldb,
    void* __restrict__ Cv, long ldc,
    const float* __restrict__ bias, const float* __restrict__ resid,
    int M, int N, int K, int nTM) {
  __shared__ u16 lds[65536];
  const int nwg = gridDim.x;
  const int qx = nwg >> 3, rx = nwg & 7;
  const int xcd = blockIdx.x & 7, seq = blockIdx.x >> 3;
  const int wg = (xcd < rx ? xcd * (qx + 1) : rx * (qx + 1) + (xcd - rx) * qx) + seq;
  const int tm = wg % nTM, tn = wg / nTM;
  const int rowA0 = tm * 256, rowB0 = tn * 256;

  const int t = threadIdx.x, w = t >> 6, l = t & 63;
  const int lrow = l & 15, kgrp = l >> 4;
  const int wr = w >> 2, wc = w & 3;

  const int srow = t >> 2;
  const int scol = ((t & 3) ^ ((t >> 3) & 3)) * 8;
  const u16* Asrc = A + (long)(rowA0 + srow) * lda + scol;
  const u16* Bsrc = Bt + (long)(rowB0 + srow) * ldb + scol;
  char* ldsB = (char*)lds;
  const int wbase = w * 1024;

  const int fswz = (kgrp ^ ((lrow >> 1) & 3)) * 8;
  const int aoff = (wr * 128 + lrow) * 32 + fswz;
  const int boff = 8192 + (wc * 64 + lrow) * 32 + fswz;

  f32x4 acc[8][4] = {};
  const int NT = K >> 5;

  #pragma unroll
  for (int pt = 0; pt < 3; pt++) {
    const int k0 = pt << 5;
    const int bb = pt * 32768;
    lds_cp16(Asrc + k0,                    ldsB + bb + wbase);
    lds_cp16(Asrc + (long)128 * lda + k0,  ldsB + bb + 8192 + wbase);
    lds_cp16(Bsrc + k0,                    ldsB + bb + 16384 + wbase);
    lds_cp16(Bsrc + (long)128 * ldb + k0,  ldsB + bb + 24576 + wbase);
  }

  for (int tt = 0; tt < NT; tt++) {
    const int rem = NT - 1 - tt;
    if (rem >= 2)      asm volatile("s_waitcnt vmcnt(8)" ::: "memory");
    else if (rem == 1) asm volatile("s_waitcnt vmcnt(4)" ::: "memory");
    else               asm volatile("s_waitcnt vmcnt(0)" ::: "memory");
    __builtin_amdgcn_sched_barrier(0);
    __builtin_amdgcn_s_barrier();

    const u16* buf = lds + (tt & 3) * 16384;
    const int stage = tt + 3 < NT;
    const int k0n = (tt + 3) << 5;
    const int bbn = ((tt + 3) & 3) * 32768;

    bf16x8 aF[4], bF[4];
    #pragma unroll
    for (int m = 0; m < 4; m++) aF[m] = *(const bf16x8*)(buf + aoff + m * 512);
    #pragma unroll
    for (int n = 0; n < 4; n++) bF[n] = *(const bf16x8*)(buf + boff + n * 512);
    if (stage) {
      lds_cp16(Asrc + k0n,                   ldsB + bbn + wbase);
      lds_cp16(Asrc + (long)128 * lda + k0n, ldsB + bbn + 8192 + wbase);
    }
    asm volatile("s_waitcnt lgkmcnt(0)" ::: "memory");
    __builtin_amdgcn_sched_barrier(0);
    __builtin_amdgcn_s_setprio(1);
    #pragma unroll
    for (int m = 0; m < 4; m++)
      #pragma unroll
      for (int n = 0; n < 4; n++)
        acc[m][n] = __builtin_amdgcn_mfma_f32_16x16x32_bf16(aF[m], bF[n], acc[m][n], 0, 0, 0);
    __builtin_amdgcn_s_setprio(0);

    #pragma unroll
    for (int m = 0; m < 4; m++) aF[m] = *(const bf16x8*)(buf + aoff + (m + 4) * 512);
    if (stage) {
      lds_cp16(Bsrc + k0n,                   ldsB + bbn + 16384 + wbase);
      lds_cp16(Bsrc + (long)128 * ldb + k0n, ldsB + bbn + 24576 + wbase);
    }
    asm volatile("s_waitcnt lgkmcnt(0)" ::: "memory");
    __builtin_amdgcn_sched_barrier(0);
    __builtin_amdgcn_s_setprio(1);
    #pragma unroll
    for (int m = 0; m < 4; m++)
      #pragma unroll
      for (int n = 0; n < 4; n++)
        acc[m + 4][n] = __builtin_amdgcn_mfma_f32_16x16x32_bf16(aF[m], bF[n], acc[m + 4][n], 0, 0, 0);
    __builtin_amdgcn_s_setprio(0);
  }

  float bvv[4];
  #pragma unroll
  for (int n = 0; n < 4; n++)
    bvv[n] = BIAS ? bias[rowB0 + wc * 64 + n * 16 + lrow] : 0.0f;
  #pragma unroll
  for (int m = 0; m < 8; m++) {
    const int row = rowA0 + wr * 128 + m * 16 + kgrp * 4;
    #pragma unroll
    for (int n = 0; n < 4; n++) {
      const int col = rowB0 + wc * 64 + n * 16 + lrow;
      #pragma unroll
      for (int j = 0; j < 4; j++) {
        float v = acc[m][n][j] + bvv[n];
        if (RELU) v = fmaxf(v, 0.0f);
        const long off = (long)(row + j) * ldc + col;
        if (RESID) v += resid[off];
        if (OUT_BF16) ((u16*)Cv)[off] = f2bf(v);
        else          ((float*)Cv)[off] = v;
      }
    }
  }
}

// =====================================================================
// 128x128-tile pipelined GEMM (proven). VTOUT transposes V-tiles to v_t.
// =====================================================================
template <bool OUT_BF16, bool BIAS, bool RELU, bool RESID, bool VTOUT>
__global__ __launch_bounds__(256) void gemm128p(
    const u16* __restrict__ A, long lda, long sA,
    const u16* __restrict__ Bt, long ldb, long sB,
    void* __restrict__ Cv, long ldc, long sC,
    const float* __restrict__ bias, const float* __restrict__ resid,
    u16* __restrict__ vtout,
    int M, int N, int K, int nTM) {
  __shared__ u16 lds[32768];
  const int nwg = gridDim.x;
  const int qx = nwg >> 3, rx = nwg & 7;
  const int xcd = blockIdx.x & 7, seq = blockIdx.x >> 3;
  const int wg = (xcd < rx ? xcd * (qx + 1) : rx * (qx + 1) + (xcd - rx) * qx) + seq;
  const int tm = wg % nTM, tn = wg / nTM;
  const int batch = blockIdx.y;
  A  += (long)batch * sA;
  Bt += (long)batch * sB;
  const int rowA0 = tm * 128, rowB0 = tn * 128;
  const int t = threadIdx.x, w = t >> 6, l = t & 63;
  const int lrow = l & 15, kgrp = l >> 4;
  const int wr = (w >> 1) << 6, wc = (w & 1) << 6;

  const int srow = t >> 2;
  const int scol = ((t & 3) ^ ((t >> 3) & 3)) * 8;
  const u16* Asrc = A + (long)(rowA0 + srow) * lda + scol;
  const u16* Bsrc = Bt + (long)(rowB0 + srow) * ldb + scol;
  char* ldsB = (char*)lds;
  const int wbase = w * 1024;

  const int swz8 = (kgrp ^ ((lrow >> 1) & 3)) * 8;
  const int aoff = (wr + lrow) * 32 + swz8;
  const int boff = 4096 + (wc + lrow) * 32 + swz8;

  f32x4 acc[4][4] = {};
  const int NT = K >> 5;

  #pragma unroll
  for (int pt = 0; pt < 3; pt++) {
    const int k0 = pt << 5;
    const int bb = pt * 16384;
    lds_cp16(Asrc + k0,                   ldsB + bb + wbase);
    lds_cp16(Asrc + (long)64 * lda + k0,  ldsB + bb + 4096 + wbase);
    lds_cp16(Bsrc + k0,                   ldsB + bb + 8192 + wbase);
    lds_cp16(Bsrc + (long)64 * ldb + k0,  ldsB + bb + 12288 + wbase);
  }

  for (int tt = 0; tt < NT; tt++) {
    const int rem = NT - 1 - tt;
    if (rem >= 2)      asm volatile("s_waitcnt vmcnt(8)" ::: "memory");
    else if (rem == 1) asm volatile("s_waitcnt vmcnt(4)" ::: "memory");
    else               asm volatile("s_waitcnt vmcnt(0)" ::: "memory");
    __builtin_amdgcn_sched_barrier(0);
    __builtin_amdgcn_s_barrier();

    const u16* buf = lds + (tt & 3) * 8192;
    const int stage = tt + 3 < NT;
    const int k0n = (tt + 3) << 5;
    const int bbn = ((tt + 3) & 3) * 16384;

    bf16x8 aF[4], bF[4];
    #pragma unroll
    for (int m = 0; m < 4; m++) aF[m] = *(const bf16x8*)(buf + aoff + m * 512);
    #pragma unroll
    for (int n = 0; n < 4; n++) bF[n] = *(const bf16x8*)(buf + boff + n * 512);
    if (stage) {
      lds_cp16(Asrc + k0n,                  ldsB + bbn + wbase);
      lds_cp16(Asrc + (long)64 * lda + k0n, ldsB + bbn + 4096 + wbase);
      lds_cp16(Bsrc + k0n,                  ldsB + bbn + 8192 + wbase);
      lds_cp16(Bsrc + (long)64 * ldb + k0n, ldsB + bbn + 12288 + wbase);
    }
    asm volatile("s_waitcnt lgkmcnt(0)" ::: "memory");
    __builtin_amdgcn_sched_barrier(0);
    __builtin_amdgcn_s_setprio(1);
    #pragma unroll
    for (int m = 0; m < 4; m++)
      #pragma unroll
      for (int n = 0; n < 4; n++)
        acc[m][n] = __builtin_amdgcn_mfma_f32_16x16x32_bf16(aF[m], bF[n], acc[m][n], 0, 0, 0);
    __builtin_amdgcn_s_setprio(0);
  }

  if (VTOUT && rowB0 >= 2048) {
    __syncthreads();
    #pragma unroll
    for (int m = 0; m < 4; m++) {
      #pragma unroll
      for (int n = 0; n < 4; n++) {
        const int c = wc + n * 16 + lrow;
        const int r = wr + m * 16 + (kgrp << 2);
        ushort4 pk;
        float v0 = acc[m][n][0], v1 = acc[m][n][1], v2 = acc[m][n][2], v3 = acc[m][n][3];
        if (BIAS) {
          const float bv = bias[rowB0 + c];
          v0 += bv; v1 += bv; v2 += bv; v3 += bv;
        }
        pk.x = f2bf(v0); pk.y = f2bf(v1); pk.z = f2bf(v2); pk.w = f2bf(v3);
        *(ushort4*)&lds[c * 136 + r] = pk;
      }
    }
    __syncthreads();
    {
      const int c = t >> 1, half = t & 1;
      const int dh = c & 63;
      const int h = ((rowB0 - 2048) >> 6) + (c >> 6);
      const int bb2 = rowA0 >> 10, t0 = rowA0 & 1023;
      u16* dst = vtout + (((size_t)(bb2 * 16 + h)) << 16) + ((size_t)dh << 10) +
                 t0 + half * 64;
      #pragma unroll
      for (int k = 0; k < 8; k++)
        *(bf16x8*)(dst + k * 8) = *(const bf16x8*)&lds[c * 136 + half * 64 + k * 8];
    }
  } else {
    const long coff = (long)batch * sC;
    #pragma unroll
    for (int m = 0; m < 4; m++) {
      #pragma unroll
      for (int n = 0; n < 4; n++) {
        const int col = rowB0 + wc + n * 16 + lrow;
        #pragma unroll
        for (int j = 0; j < 4; j++) {
          const int row = rowA0 + wr + m * 16 + (kgrp << 2) + j;
          float v = acc[m][n][j];
          if (BIAS) v += bias[col];
          if (RELU) v = fmaxf(v, 0.0f);
          const long off = coff + (long)row * ldc + col;
          if (RESID) v += resid[off];
          if (OUT_BF16) ((u16*)Cv)[off] = f2bf(v);
          else          ((float*)Cv)[off] = v;
        }
      }
    }
  }
}

extern "C" void kernel_launch(void* const* d_in, const int* in_sizes, int n_in,
                              void* d_out, int out_size, void* d_ws, size_t ws_size,
                              hipStream_t stream) {
  constexpr int Lc = 4, Tc = 1024, Dc = 1024, Hc = 16, Fc = 4096, DHc = 64;
  const int M = 2 * Tc;

  const int*   idxp       = (const int*)  d_in[0];
  const float* tok_emb    = (const float*)d_in[1];
  const float* pos_emb    = (const float*)d_in[2];
  const float* Wq         = (const float*)d_in[3];
  const float* bq         = (const float*)d_in[4];
  const float* Wk         = (const float*)d_in[5];
  const float* bk         = (const float*)d_in[6];
  const float* Wv         = (const float*)d_in[7];
  const float* bv         = (const float*)d_in[8];
  const float* Wo         = (const float*)d_in[9];
  const float* bo         = (const float*)d_in[10];
  const float* score_gain = (const float*)d_in[11];
  const float* norm1_gain = (const float*)d_in[12];
  const float* norm2_gain = (const float*)d_in[13];
  const float* W1         = (const float*)d_in[14];
  const float* b1         = (const float*)d_in[15];
  const float* W2         = (const float*)d_in[16];
  const float* b2         = (const float*)d_in[17];
  const float* final_gain = (const float*)d_in[18];
  const float* Wlm        = (const float*)d_in[19];
  const float* blm        = (const float*)d_in[20];

  char* p = (char*)d_ws;
  auto alloc = [&](size_t n) { char* r = p; p += (n + 255) & ~(size_t)255; return r; };
  u16*  wqkv_t = (u16*) alloc((size_t)Lc * 3072 * 1024 * 2);
  u16*  wo_t   = (u16*) alloc((size_t)Lc * 1024 * 1024 * 2);
  u16*  w1_t   = (u16*) alloc((size_t)Lc * 4096 * 1024 * 2);
  u16*  w2_t   = (u16*) alloc((size_t)Lc * 1024 * 4096 * 2);
  u16*  wlm_t  = (u16*) alloc((size_t)32000 * 1024 * 2);
  float* bqkv  = (float*)alloc((size_t)Lc * 3072 * 4);
  float* x     = (float*)alloc((size_t)M * 1024 * 4);
  u16*  hbuf   = (u16*) alloc((size_t)M * 1024 * 2);
  u16*  qkv    = (u16*) alloc((size_t)M * 3072 * 2);
  u16*  v_t    = (u16*) alloc((size_t)2 * Hc * DHc * Tc * 2);
  u16*  obuf   = (u16*) alloc((size_t)M * 1024 * 2);
  u16*  ffh    = (u16*) alloc((size_t)M * 4096 * 2);
  float* fpart = (float*)alloc((size_t)4 * M * 1024 * 4);

  wconv_all<<<20288, dim3(64, 4), 0, stream>>>(Wq, Wk, Wv, Wo, W1, W2, Wlm,
                                               wqkv_t, wo_t, w1_t, w2_t, wlm_t);
  bias_concat<<<48, 256, 0, stream>>>(bq, bk, bv, bqkv);
  embed_norm<<<M, 256, 0, stream>>>(idxp, tok_emb, pos_emb, norm1_gain, x, hbuf);

  for (int l = 0; l < Lc; l++) {
    // QKV (V columns transposed straight into v_t via LDS epilogue)
    gemm128p<true, true, false, false, true><<<dim3(16 * 24, 1), 256, 0, stream>>>(
        hbuf, 1024, 0, wqkv_t + (size_t)l * 3072 * 1024, 1024, 0,
        qkv, 3072, 0, bqkv + (size_t)l * 3072, nullptr, v_t, M, 3072, 1024, 16);

    attn_v5<<<dim3(32, 16, 2), 512, 0, stream>>>(qkv, v_t, obuf, score_gain, l);

    // O-proj split-K=2 -> f32 partials (grid 256, full GPU)
    gemm128p<false, false, false, false, false><<<dim3(128, 2), 256, 0, stream>>>(
        obuf, 1024, 512, wo_t + (size_t)l * 1024 * 1024, 1024, 512,
        fpart, 1024, (long)M * 1024, nullptr, nullptr, nullptr, M, 1024, 512, 16);
    // x += p0+p1+bo, then anorm(norm2) -> hbuf
    reduce_norm<2><<<M, 256, 0, stream>>>(fpart, bo + (size_t)l * Dc, x,
                                          norm2_gain + (size_t)l * Dc, hbuf);
    gemm128p<true, true, true, false, false><<<dim3(16 * 32, 1), 256, 0, stream>>>(
        hbuf, 1024, 0, w1_t + (size_t)l * Fc * Dc, 1024, 0,
        ffh, 4096, 0, b1 + (size_t)l * Fc, nullptr, nullptr, M, 4096, 1024, 16);
    gemm128p<false, false, false, false, false><<<dim3(128, 4), 256, 0, stream>>>(
        ffh, 4096, 1024, w2_t + (size_t)l * Dc * Fc, 4096, 1024,
        fpart, 1024, (long)M * 1024, nullptr, nullptr, nullptr, M, 1024, 1024, 16);
    const float* gnext = (l < Lc - 1) ? (norm1_gain + (size_t)(l + 1) * Dc) : final_gain;
    reduce_norm<4><<<M, 256, 0, stream>>>(fpart, b2 + (size_t)l * Dc, x, gnext, hbuf);
  }

  gemm256_kernel<false, true, false, false><<<dim3(1000), 512, 0, stream>>>(
      hbuf, 1024, wlm_t, 1024,
      d_out, 32000, blm, nullptr, M, 32000, 1024, 8);
}